// Round 6
// baseline (335.623 us; speedup 1.0000x reference)
//
#include <hip/hip_runtime.h>
#include <hip/hip_bf16.h>
#include <cstdint>

#define BATCH 16
#define TTOT  4096
#define DIN   512
#define DOUT  512
#define NG    8

typedef float f32x4 __attribute__((ext_vector_type(4)));
typedef short s16x8 __attribute__((ext_vector_type(8)));

__device__ __forceinline__ short f2b(float f) {
    union { __bf16 b; short s; } u; u.b = (__bf16)f; return u.s;
}

// group geometry
__device__ __constant__ short GT0[8] = {0,256,768,1536,1920,2560,3072,3648};
__device__ __constant__ short GL[8]  = {256,512,768,384,640,512,576,448};
// magic for bb = f / L_g  via  ((f>>6) * GM[g]) >> 16   (f < 12288)
__device__ __constant__ int   GM[8]  = {16385,8193,5462,10923,6554,8193,7282,9363};
// 64 (g, slice) pairs: nb_g = L_g/64 = {4,8,12,6,10,8,9,7}
__device__ __constant__ char PG[64] = {
    0,0,0,0,
    1,1,1,1,1,1,1,1,
    2,2,2,2,2,2,2,2,2,2,2,2,
    3,3,3,3,3,3,
    4,4,4,4,4,4,4,4,4,4,
    5,5,5,5,5,5,5,5,
    6,6,6,6,6,6,6,6,6,
    7,7,7,7,7,7,7};
__device__ __constant__ char PS[64] = {
    0,1,2,3,
    0,1,2,3,4,5,6,7,
    0,1,2,3,4,5,6,7,8,9,10,11,
    0,1,2,3,4,5,
    0,1,2,3,4,5,6,7,8,9,
    0,1,2,3,4,5,6,7,
    0,1,2,3,4,5,6,7,8,
    0,1,2,3,4,5,6};

// ---- Kernel 1: W fp32 -> bf16, pre-swizzled LDS-image chunks ----
// chunk c = (g*8+nc)*8+kt (8KB): image[row][bc] (row 0..63, bc 0..127) =
//   bf16 W[g][nc*64+row][kt*64 + ((bc ^ ((row&7)<<4))>>1)]
__global__ void wconv_kernel(const float* __restrict__ W, ushort* __restrict__ wbf) {
    int gid = blockIdx.x * 256 + threadIdx.x;   // 262144 granules x 16B
    int c = gid >> 9;                           // 512 granules per 8KB chunk
    int q = (gid & 511) << 4;
    int row = q >> 7;
    int bc  = q & 127;
    int kbyte = bc ^ ((row & 7) << 4);
    int kt = c & 7, nc = (c >> 3) & 7, g = c >> 6;
    const float* wp = W + ((size_t)((g << 9) + (nc << 6) + row) << 9)
                        + (kt << 6) + (kbyte >> 1);
    float4 v0 = *reinterpret_cast<const float4*>(wp);
    float4 v1 = *reinterpret_cast<const float4*>(wp + 4);
    s16x8 o;
    o[0]=f2b(v0.x); o[1]=f2b(v0.y); o[2]=f2b(v0.z); o[3]=f2b(v0.w);
    o[4]=f2b(v1.x); o[5]=f2b(v1.y); o[6]=f2b(v1.z); o[7]=f2b(v1.w);
    *reinterpret_cast<s16x8*>((char*)wbf + (size_t)c * 8192 + q) = o;
}

// ---- Kernel 2: B-stationary grouped GEMM. 512 blocks x 512 thr (8 waves).
// Block = (g, nc, slice): 1024 rows x 64 cols x K=512. B (64KB) LDS-resident,
// loaded once. A direct global->register in fragment layout, 2-slot ring.
// ZERO barriers in the main loop. 2 blocks/CU -> 16 waves/CU.
__launch_bounds__(512, 4)
__global__ void gemm_kernel(const float* __restrict__ x,
                            const ushort* __restrict__ wbf,
                            const float* __restrict__ bias,
                            float* __restrict__ out) {
    __shared__ __align__(16) char ldsB[65536];

    const int tid  = threadIdx.x;
    const int lane = tid & 63;
    const int wv   = tid >> 6;      // 0..7
    const int colf = lane & 15;
    const int kg   = lane >> 4;

    const int p    = blockIdx.x;                 // 0..511
    const int nc   = (p >> 3) & 7;
    const int pair = (p & 7) + ((p >> 6) << 3);  // same-XCD siblings share (g,slice)
    const int g    = PG[pair];
    const int s    = PS[pair];
    const int t0g  = GT0[g];
    const int Lg   = GL[g];
    const int Mg   = GM[g];

    // ---- load B (64 KB) once ----
    const char* wsrc = (const char*)wbf + (size_t)((g << 3) + nc) * 65536;
#pragma unroll
    for (int i = 0; i < 8; ++i)
        __builtin_amdgcn_global_load_lds(
            (const __attribute__((address_space(1))) void*)(wsrc + i * 8192 + tid * 16),
            (__attribute__((address_space(3))) void*)(ldsB + i * 8192 + tid * 16),
            16, 0, 0);
    asm volatile("s_waitcnt vmcnt(0)" ::: "memory");
    __builtin_amdgcn_s_barrier();

    float bv[4];
#pragma unroll
    for (int ni = 0; ni < 4; ++ni)
        bv[ni] = bias[(g << 9) + (nc << 6) + (ni << 4) + colf];

    // per-lane B LDS offsets (proven conflict-free pattern)
    const int swz = (colf & 7) << 4;
    int bcoA[4], bcoB[4];
#pragma unroll
    for (int ni = 0; ni < 4; ++ni) {
        int base = (((ni << 4) + colf) << 7) + ((kg << 4) ^ swz);
        bcoA[ni] = base;
        bcoB[ni] = base ^ 64;
    }

    const int fbase = s << 10;

    // A row -> pointer (fragment layout: lane row = colf, k-seg = kg*8)
    auto aptr = [&](int f) -> const float* {
        int bb = ((f >> 6) * Mg) >> 16;
        int tt = f - bb * Lg;
        return x + ((size_t)((bb << 12) + t0g + tt) << 9) + (kg << 3);
    };

    float4 sA[2][2][2];
    const float *a0, *a1, *na0, *na1;

#define LD(SL, KS) do {                                        \
        sA[SL][0][0] = *(const float4*)(a0 + (KS) * 32);       \
        sA[SL][0][1] = *(const float4*)(a0 + (KS) * 32 + 4);   \
        sA[SL][1][0] = *(const float4*)(a1 + (KS) * 32);       \
        sA[SL][1][1] = *(const float4*)(a1 + (KS) * 32 + 4);   \
    } while (0)

    {
        int f0 = fbase + (wv << 5);
        a0 = aptr(f0 + colf);
        a1 = aptr(f0 + 16 + colf);
    }
    LD(0, 0);
    LD(1, 1);

#pragma unroll 1
    for (int t = 0; t < 4; ++t) {
        f32x4 acc[2][4];
#pragma unroll
        for (int mi = 0; mi < 2; ++mi)
#pragma unroll
            for (int ni = 0; ni < 4; ++ni)
                acc[mi][ni] = (f32x4){0.f, 0.f, 0.f, 0.f};

#pragma unroll
        for (int ks = 0; ks < 16; ++ks) {
            // convert current slot to bf16 fragments
            s16x8 af[2];
#pragma unroll
            for (int mi = 0; mi < 2; ++mi) {
                float4 lo = sA[ks & 1][mi][0], hi = sA[ks & 1][mi][1];
                s16x8 o;
                o[0]=f2b(lo.x); o[1]=f2b(lo.y); o[2]=f2b(lo.z); o[3]=f2b(lo.w);
                o[4]=f2b(hi.x); o[5]=f2b(hi.y); o[6]=f2b(hi.z); o[7]=f2b(hi.w);
                af[mi] = o;
            }
            // refill the slot (2-step lead); tile handoff at ks=14/15
            if (ks == 13 && t < 3) {
                int f0n = fbase + ((((t + 1) << 3) + wv) << 5);
                na0 = aptr(f0n + colf);
                na1 = aptr(f0n + 16 + colf);
            }
            if (ks <= 13) {
                LD(ks & 1, ks + 2);
            } else if (t < 3) {
                if (ks == 14) { a0 = na0; a1 = na1; LD(0, 0); }
                else          { LD(1, 1); }
            }
            // B fragments from LDS + MFMA
            const char* bsl = ldsB + ((ks >> 1) << 13);
            s16x8 bf[4];
#pragma unroll
            for (int ni = 0; ni < 4; ++ni)
                bf[ni] = *(const s16x8*)(bsl + ((ks & 1) ? bcoB[ni] : bcoA[ni]));
#pragma unroll
            for (int mi = 0; mi < 2; ++mi)
#pragma unroll
                for (int ni = 0; ni < 4; ++ni)
                    acc[mi][ni] = __builtin_amdgcn_mfma_f32_16x16x32_bf16(
                        af[mi], bf[ni], acc[mi][ni], 0, 0, 0);
        }

        // ---- epilogue: direct stores (4 rows x 64B segments per instr;
        //      ni-quad fills 256B per row -> full-line writeback) ----
        const int ftile = fbase + (((t << 3) + wv) << 5);
#pragma unroll
        for (int mi = 0; mi < 2; ++mi)
#pragma unroll
            for (int j = 0; j < 4; ++j) {
                int f = ftile + (mi << 4) + (kg << 2) + j;
                int bb = ((f >> 6) * Mg) >> 16;
                int tt = f - bb * Lg;
                float* orow = out + ((size_t)((bb << 12) + t0g + tt) << 9) + (nc << 6);
#pragma unroll
                for (int ni = 0; ni < 4; ++ni)
                    orow[(ni << 4) + colf] = acc[mi][ni][j] + bv[ni];
            }
    }
#undef LD
}

// ---- Fallback (ws too small): R2-style 64x128 kernel, fp32 W path ----
__launch_bounds__(256)
__global__ void gemm_fallback(const float* __restrict__ x,
                              const float* __restrict__ W,
                              const float* __restrict__ bias,
                              float* __restrict__ out) {
    __shared__ __align__(16) char smem[49152];
    const int tid  = threadIdx.x;
    const int lane = tid & 63;
    const int wid  = tid >> 6;
    const int wm   = wid >> 1;
    const int wn   = wid & 1;
    const int p  = blockIdx.x;
    const int l  = ((p & 7) << 9) + (p >> 3);
    const int mt = l >> 2;
    const int nt = l & 3;
    const int bb = mt >> 6;
    const int t0 = (mt & 63) << 6;
    const int n0 = nt << 7;
    int g = 0;
    if (t0 >= 256)  g++; if (t0 >= 768)  g++; if (t0 >= 1536) g++;
    if (t0 >= 1920) g++; if (t0 >= 2560) g++; if (t0 >= 3072) g++;
    if (t0 >= 3648) g++;
    const int arow = tid >> 2;
    const int acol = (tid & 3) << 4;
    const float* aptr = x + ((size_t)(bb * TTOT + t0 + arow)) * DIN + acol;
    float4 a0, a1, a2, a3;
    float4 bw0[4], bw1[4];
    auto load_global = [&](int k0) {
        a0 = *(const float4*)(aptr + k0);
        a1 = *(const float4*)(aptr + k0 + 4);
        a2 = *(const float4*)(aptr + k0 + 8);
        a3 = *(const float4*)(aptr + k0 + 12);
#pragma unroll
        for (int pp = 0; pp < 4; ++pp) {
            int idx = pp * 256 + tid;
            int row = idx >> 3, seg = idx & 7;
            const float* wp = W + ((size_t)((g << 9) + n0 + row)) * DIN + k0 + (seg << 3);
            bw0[pp] = *(const float4*)(wp);
            bw1[pp] = *(const float4*)(wp + 4);
        }
    };
    auto swzf = [](int row, int bc) { return (row << 7) + (bc ^ ((row & 7) << 4)); };
    auto write_lds = [&](int buf) {
        char* ab  = smem + buf * 8192;
        char* bb_ = smem + 16384 + buf * 16384;
        s16x8 w0, w1;
        w0[0]=f2b(a0.x); w0[1]=f2b(a0.y); w0[2]=f2b(a0.z); w0[3]=f2b(a0.w);
        w0[4]=f2b(a1.x); w0[5]=f2b(a1.y); w0[6]=f2b(a1.z); w0[7]=f2b(a1.w);
        w1[0]=f2b(a2.x); w1[1]=f2b(a2.y); w1[2]=f2b(a2.z); w1[3]=f2b(a2.w);
        w1[4]=f2b(a3.x); w1[5]=f2b(a3.y); w1[6]=f2b(a3.z); w1[7]=f2b(a3.w);
        const int abase2 = acol << 1;
        *(s16x8*)(ab + swzf(arow, abase2))      = w0;
        *(s16x8*)(ab + swzf(arow, abase2 + 16)) = w1;
#pragma unroll
        for (int pp = 0; pp < 4; ++pp) {
            int idx = pp * 256 + tid;
            int row = idx >> 3, seg = idx & 7;
            s16x8 wvv;
            wvv[0]=f2b(bw0[pp].x); wvv[1]=f2b(bw0[pp].y);
            wvv[2]=f2b(bw0[pp].z); wvv[3]=f2b(bw0[pp].w);
            wvv[4]=f2b(bw1[pp].x); wvv[5]=f2b(bw1[pp].y);
            wvv[6]=f2b(bw1[pp].z); wvv[7]=f2b(bw1[pp].w);
            *(s16x8*)(bb_ + swzf(row, seg << 4)) = wvv;
        }
    };
    f32x4 acc[2][4];
#pragma unroll
    for (int mi = 0; mi < 2; ++mi)
#pragma unroll
        for (int ni = 0; ni < 4; ++ni) acc[mi][ni] = (f32x4){0.f,0.f,0.f,0.f};
    const int colf = lane & 15;
    const int kgrp = lane >> 4;
    auto compute = [&](int buf) {
        const char* ab  = smem + buf * 8192;
        const char* bb_ = smem + 16384 + buf * 16384;
#pragma unroll
        for (int ks = 0; ks < 2; ++ks) {
            const int kb = ks * 64 + kgrp * 16;
            s16x8 af[2], bf[4];
#pragma unroll
            for (int mi = 0; mi < 2; ++mi)
                af[mi] = *(const s16x8*)(ab + swzf(wm * 32 + mi * 16 + colf, kb));
#pragma unroll
            for (int ni = 0; ni < 4; ++ni)
                bf[ni] = *(const s16x8*)(bb_ + swzf(wn * 64 + ni * 16 + colf, kb));
#pragma unroll
            for (int mi = 0; mi < 2; ++mi)
#pragma unroll
                for (int ni = 0; ni < 4; ++ni)
                    acc[mi][ni] = __builtin_amdgcn_mfma_f32_16x16x32_bf16(
                        af[mi], bf[ni], acc[mi][ni], 0, 0, 0);
        }
    };
    load_global(0);
    write_lds(0);
    __syncthreads();
    int buf = 0;
#pragma unroll 1
    for (int kt = 0; kt < 8; ++kt) {
        if (kt < 7) load_global((kt + 1) << 6);
        compute(buf);
        if (kt < 7) write_lds(buf ^ 1);
        __syncthreads();
        buf ^= 1;
    }
    float* cbuf = (float*)smem;
#pragma unroll
    for (int ni = 0; ni < 4; ++ni) {
        const int c = wn * 64 + ni * 16 + colf;
#pragma unroll
        for (int mi = 0; mi < 2; ++mi) {
            const int r = wm * 32 + mi * 16 + kgrp * 4;
            f32x4 v = acc[mi][ni];
            cbuf[(r + 0) * 132 + c] = v[0];
            cbuf[(r + 1) * 132 + c] = v[1];
            cbuf[(r + 2) * 132 + c] = v[2];
            cbuf[(r + 3) * 132 + c] = v[3];
        }
    }
    __syncthreads();
    const int rr = tid >> 5;
    const int cc = (tid & 31) << 2;
    const float4 bvv = *(const float4*)(bias + (g << 9) + n0 + cc);
#pragma unroll
    for (int it = 0; it < 8; ++it) {
        const int row = it * 8 + rr;
        float4 v = *(const float4*)(cbuf + row * 132 + cc);
        float4 o4; o4.x = v.x + bvv.x; o4.y = v.y + bvv.y;
                   o4.z = v.z + bvv.z; o4.w = v.w + bvv.w;
        *(float4*)(out + ((size_t)(bb * TTOT) + t0 + row) * DOUT + n0 + cc) = o4;
    }
}

extern "C" void kernel_launch(void* const* d_in, const int* in_sizes, int n_in,
                              void* d_out, int out_size, void* d_ws, size_t ws_size,
                              hipStream_t stream) {
    const float* x    = (const float*)d_in[0];
    const float* W    = (const float*)d_in[1];
    const float* bias = (const float*)d_in[2];
    float* out = (float*)d_out;

    const size_t wbytes = (size_t)NG * DOUT * DIN * sizeof(ushort);  // 4 MB

    if (ws_size >= wbytes) {
        ushort* wbf = (ushort*)d_ws;
        wconv_kernel<<<1024, 256, 0, stream>>>(W, wbf);
        gemm_kernel<<<512, 512, 0, stream>>>(x, wbf, bias, out);
    } else {
        gemm_fallback<<<BATCH * 64 * 4, 256, 0, stream>>>(x, W, bias, out);
    }
}

// Round 7
// 115.205 us; speedup vs baseline: 2.9133x; 2.9133x over previous
//
#include <hip/hip_runtime.h>
#include <hip/hip_bf16.h>
#include <cstdint>

#define BATCH 16
#define TTOT  4096
#define DIN   512
#define DOUT  512
#define NG    8
#define NJB   18     // m-jobs per batch at BM=256 (16 full + stubs)
#define NKT   8      // K tiles of 64

typedef float f32x4 __attribute__((ext_vector_type(4)));
typedef short s16x8 __attribute__((ext_vector_type(8)));

__device__ __forceinline__ short f2b(float f) {
    union { __bf16 b; short s; } u; u.b = (__bf16)f; return u.s;
}

// M-job tables (BM=256): (t0, group, valid_rows) per batch.
__device__ __constant__ short JT0[NJB] = {
    0,256,512,768,1024,1280,1536,1792,1920,2176,2432,2560,2816,3072,3328,3584,3648,3904};
__device__ __constant__ char JG[NJB] = {
    0,1,1,2,2,2,3,3,4,4,4,5,5,6,6,6,7,7};
__device__ __constant__ short JVR[NJB] = {
    256,256,256,256,256,256,256,128,256,256,128,256,256,256,256,64,256,192};

// ---- Kernel 1: W fp32 -> bf16, pre-swizzled 256-row LDS-image chunks ----
// chunk c = (g*2+nt)*8+kt (32KB): image[row<256][bc<128] =
//   bf16 W[g][nt*256+row][kt*64 + ((bc ^ ((row&7)<<4))>>1)]
__global__ void wconv_kernel(const float* __restrict__ W, ushort* __restrict__ wbf) {
    int gid = blockIdx.x * 256 + threadIdx.x;   // 262144 granules x 16B
    int c = gid >> 11;                          // 0..127
    int q = (gid & 2047) << 4;                  // byte in chunk
    int row = q >> 7;                           // 0..255
    int bc  = q & 127;
    int kbyte = bc ^ ((row & 7) << 4);
    int kt = c & 7, nt = (c >> 3) & 1, g = c >> 4;
    const float* wp = W + ((size_t)((g << 9) + (nt << 8) + row) << 9)
                        + (kt << 6) + (kbyte >> 1);
    float4 v0 = *reinterpret_cast<const float4*>(wp);
    float4 v1 = *reinterpret_cast<const float4*>(wp + 4);
    s16x8 o;
    o[0]=f2b(v0.x); o[1]=f2b(v0.y); o[2]=f2b(v0.z); o[3]=f2b(v0.w);
    o[4]=f2b(v1.x); o[5]=f2b(v1.y); o[6]=f2b(v1.z); o[7]=f2b(v1.w);
    *reinterpret_cast<s16x8*>((char*)wbf + (size_t)c * 32768 + q) = o;
}

// ---- Kernel 2: grouped GEMM 256x256x64, 8 waves (2Mx4N), wave-tile 128x64.
// A reg-staged fp32->bf16 (dbuf-2), B global_load_lds (dbuf-2, pre-swizzled),
// one barrier per K-tile, counted vmcnt(8) steady state. ----
__launch_bounds__(512, 2)
__global__ void gemm_kernel(const float* __restrict__ x,
                            const ushort* __restrict__ wbf,
                            const float* __restrict__ bias,
                            float* __restrict__ out) {
    // [A0 32K][A1 32K][B0 32K][B1 32K]; epilogue C overlays A region (64K)
    __shared__ __align__(16) char smem[131072];

    const int tid  = threadIdx.x;
    const int lane = tid & 63;
    const int wv   = tid >> 6;      // 0..7
    const int wm   = wv >> 2;       // 0..1 : 128-row slab
    const int wn   = wv & 3;        // 0..3 : 64-col slab
    const int colf = lane & 15;
    const int kg   = lane >> 4;

    const int p     = blockIdx.x;     // 0..575
    const int mjob  = p >> 1;
    const int nt    = p & 1;
    const int batch = mjob / NJB;
    const int j     = mjob - batch * NJB;
    const int t0    = JT0[j];
    const int g     = JG[j];
    const int vr    = JVR[j];
    const int n0    = nt << 8;

    const char* bchunk = (const char*)wbf + (size_t)(((g << 1) + nt) << 3) * 32768;

    // A staging: thread -> row r = tid>>1 (0..255), half h = tid&1 (32 f32 cols)
    const int r = tid >> 1;
    const int h = tid & 1;
    const int re = (r < vr) ? r : (vr - 1);                 // clamp stub rows
    const float* arow_ptr = x + (((size_t)(batch * TTOT + t0 + re)) << 9) + (h << 5);

    float4 st[4][2];

#define ISSUE_A(KT_) do {                                                   \
        _Pragma("unroll")                                                   \
        for (int j4 = 0; j4 < 4; ++j4) {                                    \
            const float* p_ = arow_ptr + ((KT_) << 6) + (j4 << 3);          \
            st[j4][0] = *(const float4*)(p_);                               \
            st[j4][1] = *(const float4*)(p_ + 4);                           \
        }                                                                   \
    } while (0)

#define CVT_WRITE_A(KT_) do {                                               \
        char* ab_ = smem + ((KT_) & 1) * 32768;                             \
        _Pragma("unroll")                                                   \
        for (int j4 = 0; j4 < 4; ++j4) {                                    \
            float4 lo_ = st[j4][0], hi_ = st[j4][1];                        \
            s16x8 o_;                                                       \
            o_[0]=f2b(lo_.x); o_[1]=f2b(lo_.y); o_[2]=f2b(lo_.z); o_[3]=f2b(lo_.w); \
            o_[4]=f2b(hi_.x); o_[5]=f2b(hi_.y); o_[6]=f2b(hi_.z); o_[7]=f2b(hi_.w); \
            int bc_ = ((h << 6) + (j4 << 4)) ^ ((r & 7) << 4);              \
            *(s16x8*)(ab_ + (r << 7) + bc_) = o_;                           \
        }                                                                   \
    } while (0)

#define ISSUE_B(KT_) do {                                                   \
        const char* src_ = bchunk + (size_t)(KT_) * 32768 + tid * 16;       \
        char* dst_ = smem + 65536 + ((KT_) & 1) * 32768 + tid * 16;         \
        _Pragma("unroll")                                                   \
        for (int i_ = 0; i_ < 4; ++i_) {                                    \
            __builtin_amdgcn_global_load_lds(                               \
                (const __attribute__((address_space(1))) void*)(src_ + i_ * 8192), \
                (__attribute__((address_space(3))) void*)(dst_ + i_ * 8192),\
                16, 0, 0);                                                  \
        }                                                                   \
    } while (0)

#define COMPUTE(KT_) do {                                                   \
        const char* ab_ = smem + ((KT_) & 1) * 32768;                       \
        const char* bb_ = smem + 65536 + ((KT_) & 1) * 32768;               \
        __builtin_amdgcn_s_setprio(1);                                      \
        _Pragma("unroll")                                                   \
        for (int ks = 0; ks < 2; ++ks) {                                    \
            const int kb = ks * 64 + (kg << 4);                             \
            s16x8 bf[4];                                                    \
            _Pragma("unroll")                                               \
            for (int ni = 0; ni < 4; ++ni) {                                \
                int rr_ = wn * 64 + ni * 16 + colf;                         \
                bf[ni] = *(const s16x8*)(bb_ + (rr_ << 7) + (kb ^ ((rr_ & 7) << 4))); \
            }                                                               \
            _Pragma("unroll")                                               \
            for (int mi = 0; mi < 8; ++mi) {                                \
                int rr_ = wm * 128 + mi * 16 + colf;                        \
                s16x8 af = *(const s16x8*)(ab_ + (rr_ << 7) + (kb ^ ((rr_ & 7) << 4))); \
                _Pragma("unroll")                                           \
                for (int ni = 0; ni < 4; ++ni)                              \
                    acc[mi][ni] = __builtin_amdgcn_mfma_f32_16x16x32_bf16(  \
                        af, bf[ni], acc[mi][ni], 0, 0, 0);                  \
            }                                                               \
        }                                                                   \
        __builtin_amdgcn_s_setprio(0);                                      \
    } while (0)

#define FENCE  asm volatile("" ::: "memory")
#define WAITV8 asm volatile("s_waitcnt vmcnt(8)" ::: "memory")
#define WAITV0 asm volatile("s_waitcnt vmcnt(0)" ::: "memory")
#define WAITL0 asm volatile("s_waitcnt lgkmcnt(0)" ::: "memory")
#define BARRIER do { FENCE; __builtin_amdgcn_s_barrier(); FENCE; } while (0)

    f32x4 acc[8][4];
#pragma unroll
    for (int mi = 0; mi < 8; ++mi)
#pragma unroll
        for (int ni = 0; ni < 4; ++ni)
            acc[mi][ni] = (f32x4){0.f, 0.f, 0.f, 0.f};

    // ---- prologue ----
    ISSUE_A(0); ISSUE_B(0);
    FENCE;
    CVT_WRITE_A(0);            // compiler waits the 8 A(0) loads
    ISSUE_A(1);
    FENCE;
    WAITV8;                    // B(0) landed; A(1)'s 8 ride on
    WAITL0;
    BARRIER;

#pragma unroll
    for (int kt = 0; kt < NKT; ++kt) {
        if (kt + 1 < NKT) { ISSUE_B(kt + 1); FENCE; }
        COMPUTE(kt);
        if (kt + 1 < NKT) {
            CVT_WRITE_A(kt + 1);           // compiler waits A(kt+1)
            if (kt + 2 < NKT) { ISSUE_A(kt + 2); FENCE; WAITV8; }
            else              { WAITV0; }  // kt==6: only B(7) outstanding
            WAITL0;
            BARRIER;
        }
    }

    WAITL0;
    BARRIER;   // all LDS reads done before C overlay of A region

    // ---- epilogue: 8 passes of 32 rows via LDS transpose (stride 260) ----
    float* cbuf = (float*)smem;            // 32*260*4 = 33.3KB < 64KB A region
    float4 bv4[4];
    const int er = tid >> 4;               // 0..31
    const int ec = (tid & 15) << 2;        // f32 col quad base
#pragma unroll
    for (int i = 0; i < 4; ++i)
        bv4[i] = *(const float4*)(bias + (g << 9) + n0 + ec + (i << 6));

#pragma unroll
    for (int pp = 0; pp < 8; ++pp) {
        if ((wv >> 2) == (pp >> 2)) {
#pragma unroll
            for (int m = 0; m < 2; ++m) {
                const int am = (pp & 3) * 2 + m;
#pragma unroll
                for (int ni = 0; ni < 4; ++ni) {
                    const int base = (m * 16 + kg * 4) * 260 + wn * 64 + ni * 16 + colf;
                    cbuf[base]       = acc[am][ni][0];
                    cbuf[base + 260] = acc[am][ni][1];
                    cbuf[base + 520] = acc[am][ni][2];
                    cbuf[base + 780] = acc[am][ni][3];
                }
            }
        }
        WAITL0;
        BARRIER;
        const int row = pp * 32 + er;
        if (row < vr) {
            float* orow = out + (((size_t)(batch * TTOT + t0 + row)) << 9) + n0;
#pragma unroll
            for (int i = 0; i < 4; ++i) {
                float4 v = *(const float4*)(cbuf + er * 260 + ec + (i << 6));
                float4 o4;
                o4.x = v.x + bv4[i].x; o4.y = v.y + bv4[i].y;
                o4.z = v.z + bv4[i].z; o4.w = v.w + bv4[i].w;
                *(float4*)(orow + ec + (i << 6)) = o4;
            }
        }
        BARRIER;   // protect cbuf before next pass overwrites
    }
#undef ISSUE_A
#undef CVT_WRITE_A
#undef ISSUE_B
#undef COMPUTE
#undef FENCE
#undef WAITV8
#undef WAITV0
#undef WAITL0
#undef BARRIER
}

// ---- Fallback (ws too small): R2-style 64x128 kernel, fp32 W path ----
__launch_bounds__(256)
__global__ void gemm_fallback(const float* __restrict__ x,
                              const float* __restrict__ W,
                              const float* __restrict__ bias,
                              float* __restrict__ out) {
    __shared__ __align__(16) char smem[49152];
    const int tid  = threadIdx.x;
    const int lane = tid & 63;
    const int wid  = tid >> 6;
    const int wm   = wid >> 1;
    const int wn   = wid & 1;
    const int p  = blockIdx.x;
    const int l  = ((p & 7) << 9) + (p >> 3);
    const int mt = l >> 2;
    const int nt = l & 3;
    const int bb = mt >> 6;
    const int t0 = (mt & 63) << 6;
    const int n0 = nt << 7;
    int g = 0;
    if (t0 >= 256)  g++; if (t0 >= 768)  g++; if (t0 >= 1536) g++;
    if (t0 >= 1920) g++; if (t0 >= 2560) g++; if (t0 >= 3072) g++;
    if (t0 >= 3648) g++;
    const int arow = tid >> 2;
    const int acol = (tid & 3) << 4;
    const float* aptr = x + ((size_t)(bb * TTOT + t0 + arow)) * DIN + acol;
    float4 a0, a1, a2, a3;
    float4 bw0[4], bw1[4];
    auto load_global = [&](int k0) {
        a0 = *(const float4*)(aptr + k0);
        a1 = *(const float4*)(aptr + k0 + 4);
        a2 = *(const float4*)(aptr + k0 + 8);
        a3 = *(const float4*)(aptr + k0 + 12);
#pragma unroll
        for (int pp = 0; pp < 4; ++pp) {
            int idx = pp * 256 + tid;
            int row = idx >> 3, seg = idx & 7;
            const float* wp = W + ((size_t)((g << 9) + n0 + row)) * DIN + k0 + (seg << 3);
            bw0[pp] = *(const float4*)(wp);
            bw1[pp] = *(const float4*)(wp + 4);
        }
    };
    auto swzf = [](int row, int bc) { return (row << 7) + (bc ^ ((row & 7) << 4)); };
    auto write_lds = [&](int buf) {
        char* ab  = smem + buf * 8192;
        char* bb_ = smem + 16384 + buf * 16384;
        s16x8 w0, w1;
        w0[0]=f2b(a0.x); w0[1]=f2b(a0.y); w0[2]=f2b(a0.z); w0[3]=f2b(a0.w);
        w0[4]=f2b(a1.x); w0[5]=f2b(a1.y); w0[6]=f2b(a1.z); w0[7]=f2b(a1.w);
        w1[0]=f2b(a2.x); w1[1]=f2b(a2.y); w1[2]=f2b(a2.z); w1[3]=f2b(a2.w);
        w1[4]=f2b(a3.x); w1[5]=f2b(a3.y); w1[6]=f2b(a3.z); w1[7]=f2b(a3.w);
        const int abase2 = acol << 1;
        *(s16x8*)(ab + swzf(arow, abase2))      = w0;
        *(s16x8*)(ab + swzf(arow, abase2 + 16)) = w1;
#pragma unroll
        for (int pp = 0; pp < 4; ++pp) {
            int idx = pp * 256 + tid;
            int row = idx >> 3, seg = idx & 7;
            s16x8 wvv;
            wvv[0]=f2b(bw0[pp].x); wvv[1]=f2b(bw0[pp].y);
            wvv[2]=f2b(bw0[pp].z); wvv[3]=f2b(bw0[pp].w);
            wvv[4]=f2b(bw1[pp].x); wvv[5]=f2b(bw1[pp].y);
            wvv[6]=f2b(bw1[pp].z); wvv[7]=f2b(bw1[pp].w);
            *(s16x8*)(bb_ + swzf(row, seg << 4)) = wvv;
        }
    };
    f32x4 acc[2][4];
#pragma unroll
    for (int mi = 0; mi < 2; ++mi)
#pragma unroll
        for (int ni = 0; ni < 4; ++ni) acc[mi][ni] = (f32x4){0.f,0.f,0.f,0.f};
    const int colf = lane & 15;
    const int kgrp = lane >> 4;
    auto compute = [&](int buf) {
        const char* ab  = smem + buf * 8192;
        const char* bb_ = smem + 16384 + buf * 16384;
#pragma unroll
        for (int ks = 0; ks < 2; ++ks) {
            const int kb = ks * 64 + kgrp * 16;
            s16x8 af[2], bf[4];
#pragma unroll
            for (int mi = 0; mi < 2; ++mi)
                af[mi] = *(const s16x8*)(ab + swzf(wm * 32 + mi * 16 + colf, kb));
#pragma unroll
            for (int ni = 0; ni < 4; ++ni)
                bf[ni] = *(const s16x8*)(bb_ + swzf(wn * 64 + ni * 16 + colf, kb));
#pragma unroll
            for (int mi = 0; mi < 2; ++mi)
#pragma unroll
                for (int ni = 0; ni < 4; ++ni)
                    acc[mi][ni] = __builtin_amdgcn_mfma_f32_16x16x32_bf16(
                        af[mi], bf[ni], acc[mi][ni], 0, 0, 0);
        }
    };
    load_global(0);
    write_lds(0);
    __syncthreads();
    int buf = 0;
#pragma unroll 1
    for (int kt = 0; kt < 8; ++kt) {
        if (kt < 7) load_global((kt + 1) << 6);
        compute(buf);
        if (kt < 7) write_lds(buf ^ 1);
        __syncthreads();
        buf ^= 1;
    }
    float* cbuf = (float*)smem;
#pragma unroll
    for (int ni = 0; ni < 4; ++ni) {
        const int c = wn * 64 + ni * 16 + colf;
#pragma unroll
        for (int mi = 0; mi < 2; ++mi) {
            const int r = wm * 32 + mi * 16 + kgrp * 4;
            f32x4 v = acc[mi][ni];
            cbuf[(r + 0) * 132 + c] = v[0];
            cbuf[(r + 1) * 132 + c] = v[1];
            cbuf[(r + 2) * 132 + c] = v[2];
            cbuf[(r + 3) * 132 + c] = v[3];
        }
    }
    __syncthreads();
    const int rr = tid >> 5;
    const int cc = (tid & 31) << 2;
    const float4 bvv = *(const float4*)(bias + (g << 9) + n0 + cc);
#pragma unroll
    for (int it = 0; it < 8; ++it) {
        const int row = it * 8 + rr;
        float4 v = *(const float4*)(cbuf + row * 132 + cc);
        float4 o4; o4.x = v.x + bvv.x; o4.y = v.y + bvv.y;
                   o4.z = v.z + bvv.z; o4.w = v.w + bvv.w;
        *(float4*)(out + ((size_t)(bb * TTOT) + t0 + row) * DOUT + n0 + cc) = o4;
    }
}

extern "C" void kernel_launch(void* const* d_in, const int* in_sizes, int n_in,
                              void* d_out, int out_size, void* d_ws, size_t ws_size,
                              hipStream_t stream) {
    const float* x    = (const float*)d_in[0];
    const float* W    = (const float*)d_in[1];
    const float* bias = (const float*)d_in[2];
    float* out = (float*)d_out;

    const size_t wbytes = (size_t)NG * DOUT * DIN * sizeof(ushort);  // 4 MB

    if (ws_size >= wbytes) {
        ushort* wbf = (ushort*)d_ws;
        wconv_kernel<<<1024, 256, 0, stream>>>(W, wbf);
        gemm_kernel<<<NJB * BATCH * 2, 512, 0, stream>>>(x, wbf, bias, out);
    } else {
        gemm_fallback<<<BATCH * 64 * 4, 256, 0, stream>>>(x, W, bias, out);
    }
}